// Round 23
// baseline (473.701 us; speedup 1.0000x reference)
//
#include <hip/hip_runtime.h>

#define N_NODES 100000
#define N_PAD   100032   // 1563 * 64 -- padded node count for guard-free staging
#define N_EDGES 1600000
#define T_STEPS 6
#define FDIM    64
#define SEG     (T_STEPS * N_NODES)
#define C2      0.01f
#define PADF    68   // LDS row stride: 17 quads, 16B-aligned float4 rows
#define RFL __builtin_amdgcn_readfirstlane

// ===== VERBATIM r22 k_build (int2-packed edge data) =====
__global__ __launch_bounds__(256) void k_build(
    const int* __restrict__ src, const int* __restrict__ dst,
    const int* __restrict__ tix, int* __restrict__ head,
    int2* __restrict__ edat)
{
  const int e = blockIdx.x * blockDim.x + threadIdx.x;
  if (e >= N_EDGES) return;
  const int key = tix[e] * N_NODES + dst[e];
  const int prev = atomicExch(&head[key], e);
  edat[e] = make_int2(src[e], prev);
}

// ===== VERBATIM r22 k_sum6 (scalarized 6-chain walk, fused 8B index load) =====
__global__ __launch_bounds__(256) void k_sum6(
    const float* __restrict__ feat, const int2* __restrict__ edat,
    const int* __restrict__ head, float* __restrict__ sums,
    float* __restrict__ cnt)
{
  const int lane = threadIdx.x & 63;
  const int n = blockIdx.x * (blockDim.x >> 6) + (threadIdx.x >> 6);
  if (n >= N_NODES) return;

  int e0 = RFL(head[(size_t)0 * N_NODES + n]);
  int e1 = RFL(head[(size_t)1 * N_NODES + n]);
  int e2 = RFL(head[(size_t)2 * N_NODES + n]);
  int e3 = RFL(head[(size_t)3 * N_NODES + n]);
  int e4 = RFL(head[(size_t)4 * N_NODES + n]);
  int e5 = RFL(head[(size_t)5 * N_NODES + n]);

  float v0 = 0.f, v1 = 0.f, v2 = 0.f, v3 = 0.f, v4 = 0.f, v5 = 0.f;
  int c0 = 0, c1 = 0, c2 = 0, c3 = 0, c4 = 0, c5 = 0;

  while ((e0 >= 0) | (e1 >= 0) | (e2 >= 0) | (e3 >= 0) | (e4 >= 0) | (e5 >= 0)) {
    const int a0 = e0 < 0 ? 0 : e0, a1 = e1 < 0 ? 0 : e1, a2 = e2 < 0 ? 0 : e2;
    const int a3 = e3 < 0 ? 0 : e3, a4 = e4 < 0 ? 0 : e4, a5 = e5 < 0 ? 0 : e5;

    const int2 d0 = edat[a0];
    const int2 d1 = edat[a1];
    const int2 d2 = edat[a2];
    const int2 d3 = edat[a3];
    const int2 d4 = edat[a4];
    const int2 d5 = edat[a5];

    const int s0 = RFL(d0.x), x0 = RFL(d0.y);
    const int s1 = RFL(d1.x), x1 = RFL(d1.y);
    const int s2 = RFL(d2.x), x2 = RFL(d2.y);
    const int s3 = RFL(d3.x), x3 = RFL(d3.y);
    const int s4 = RFL(d4.x), x4 = RFL(d4.y);
    const int s5 = RFL(d5.x), x5 = RFL(d5.y);

    const float f0 = feat[(size_t)s0 * FDIM + lane];
    const float f1 = feat[(size_t)s1 * FDIM + lane];
    const float f2 = feat[(size_t)s2 * FDIM + lane];
    const float f3 = feat[(size_t)s3 * FDIM + lane];
    const float f4 = feat[(size_t)s4 * FDIM + lane];
    const float f5 = feat[(size_t)s5 * FDIM + lane];

    v0 += (e0 >= 0) ? f0 : 0.0f;  c0 += (e0 >= 0);  e0 = (e0 >= 0) ? x0 : -1;
    v1 += (e1 >= 0) ? f1 : 0.0f;  c1 += (e1 >= 0);  e1 = (e1 >= 0) ? x1 : -1;
    v2 += (e2 >= 0) ? f2 : 0.0f;  c2 += (e2 >= 0);  e2 = (e2 >= 0) ? x2 : -1;
    v3 += (e3 >= 0) ? f3 : 0.0f;  c3 += (e3 >= 0);  e3 = (e3 >= 0) ? x3 : -1;
    v4 += (e4 >= 0) ? f4 : 0.0f;  c4 += (e4 >= 0);  e4 = (e4 >= 0) ? x4 : -1;
    v5 += (e5 >= 0) ? f5 : 0.0f;  c5 += (e5 >= 0);  e5 = (e5 >= 0) ? x5 : -1;
  }

  sums[((size_t)0 * N_PAD + n) * FDIM + lane] = v0;
  sums[((size_t)1 * N_PAD + n) * FDIM + lane] = v1;
  sums[((size_t)2 * N_PAD + n) * FDIM + lane] = v2;
  sums[((size_t)3 * N_PAD + n) * FDIM + lane] = v3;
  sums[((size_t)4 * N_PAD + n) * FDIM + lane] = v4;
  sums[((size_t)5 * N_PAD + n) * FDIM + lane] = v5;
  if (lane == 0) {
    cnt[(size_t)0 * N_NODES + n] = (float)c0;
    cnt[(size_t)1 * N_NODES + n] = (float)c1;
    cnt[(size_t)2 * N_NODES + n] = (float)c2;
    cnt[(size_t)3 * N_NODES + n] = (float)c3;
    cnt[(size_t)4 * N_NODES + n] = (float)c4;
    cnt[(size_t)5 * N_NODES + n] = (float)c5;
  }
}

// Pass A hoisted out of the gemm (where the 4 j-slice waves computed it 4x
// redundantly -- ~45% of gemm instructions). One thread per (t,n), verbatim
// r1's ORIGINAL global-read pass A (the exact expression/load form that
// passed at absmax 128). Transforms cnt -> s IN PLACE (read own element,
// overwrite): zero extra workspace, per-thread ordering trivially safe.
__global__ __launch_bounds__(256) void k_scale(
    const float* __restrict__ sums, float* __restrict__ cs)
{
  const int n = blockIdx.x * 256 + threadIdx.x;
  const int t = blockIdx.y;
  if (n >= N_NODES) return;
  const float c  = cs[(size_t)t * N_NODES + n];
  const float rc = 1.0f / fmaxf(c, 1.0f);
  const float4* row = (const float4*)(sums + ((size_t)t * N_PAD + n) * FDIM);
  float ss = 0.0f;
  #pragma unroll
  for (int q = 0; q < FDIM / 4; ++q) {
    float4 v = row[q];
    float m0 = v.x * rc, m1 = v.y * rc, m2 = v.z * rc, m3 = v.w * rc;
    ss += m0 * m0 + m1 * m1 + m2 * m2 + m3 * m3;
  }
  const float norm = 1.0f - C2 * ss;
  cs[(size_t)t * N_NODES + n] = rc / norm;
}

// Pure pass-B gemm (r22's tile2 minus pass A): per-thread LDS reads halve
// (192 -> 96 b128), divides vanish, s loaded per (t,n) as one coalesced
// 4B L2-hot load. hs = hv[i]*s sees bit-identical s -> pass B rounding
// untouched. Staging, jb-scalarization, two-plane rounds all verbatim r22.
template <int OUTF, int JBLK>
__global__ __launch_bounds__(256) void k_gemm_b(
    const float* __restrict__ sums, const float* __restrict__ cs,
    const float* __restrict__ W, const float* __restrict__ bias,
    float* __restrict__ out)
{
  __shared__ float lds[2][64 * PADF];   // 2 planes x 17408 B
  const int tid = threadIdx.x;
  const int lane = tid & 63;
  const int n0 = blockIdx.x * 64;
  const int jb = RFL(tid >> 6) * JBLK;

  int n = n0 + lane;
  const bool valid = (n < N_NODES);
  if (!valid) n = N_NODES - 1;

  float acc[JBLK];
  #pragma unroll
  for (int j = 0; j < JBLK; ++j) acc[j] = bias[jb + j];

  #pragma unroll 1
  for (int tp = 0; tp < T_STEPS / 2; ++tp) {
    __syncthreads();
    float4 reg[8];
    #pragma unroll
    for (int it = 0; it < 8; ++it) {
      const int item = tid + it * 256;
      const int q = item & 15;
      const int u = (item >> 4) & 63;
      const int pl = item >> 10;
      reg[it] = *(const float4*)(sums + ((size_t)(2 * tp + pl) * N_PAD + n0 + u) * FDIM + q * 4);
    }
    #pragma unroll
    for (int it = 0; it < 8; ++it) {
      const int item = tid + it * 256;
      const int q = item & 15;
      const int u = (item >> 4) & 63;
      const int pl = item >> 10;
      *(float4*)(&lds[pl][u * PADF + q * 4]) = reg[it];
    }
    __syncthreads();

    #pragma unroll
    for (int pl = 0; pl < 2; ++pl) {
      const int t = 2 * tp + pl;
      const float s = cs[(size_t)t * N_NODES + n];   // precomputed rc/norm
      const float4* row = (const float4*)(&lds[pl][lane * PADF]);

      #pragma unroll
      for (int q8 = 0; q8 < FDIM / 8; ++q8) {
        const float4 a = row[q8 * 2 + 0];
        const float4 b4 = row[q8 * 2 + 1];
        const float hv[8] = {a.x, a.y, a.z, a.w, b4.x, b4.y, b4.z, b4.w};
        const float* wr = W + ((size_t)t * FDIM + q8 * 8) * OUTF + jb;
        #pragma unroll
        for (int i = 0; i < 8; ++i) {
          const float hs = hv[i] * s;
          #pragma unroll
          for (int j = 0; j < JBLK; ++j)
            acc[j] = fmaf(hs, wr[i * OUTF + j], acc[j]);
        }
      }
    }
  }

  if (valid) {
    float* o = out + (size_t)n * OUTF + jb;
    #pragma unroll
    for (int j = 0; j < JBLK; ++j) o[j] = fmaxf(acc[j], 0.0f);
  }
}

extern "C" void kernel_launch(void* const* d_in, const int* in_sizes, int n_in,
                              void* d_out, int out_size, void* d_ws, size_t ws_size,
                              hipStream_t stream) {
  const float* x  = (const float*)d_in[0];
  const int*  ei  = (const int*)d_in[1];
  const int*  tix = (const int*)d_in[2];
  const float* W1 = (const float*)d_in[3];
  const float* b1 = (const float*)d_in[4];
  const float* W2 = (const float*)d_in[5];
  const float* b2 = (const float*)d_in[6];

  const int* src = ei;
  const int* dst = ei + N_EDGES;

  // Workspace (196.9MB, same as passing r22): head[SEG] (2.4MB) | edat[NE]
  // int2 (12.8MB) | sums[6*N_PAD*64] | cs[SEG] (cnt, transformed to s
  // in place by k_scale) | h1[N_PAD*64]. head+edat = 15.2MB = 256B-multiple
  // -> sums rows 256B-aligned (r21 lesson).
  int*   head = (int*)d_ws;
  int2*  edat = (int2*)(head + SEG);
  float* sums = (float*)(edat + N_EDGES);
  float* cs   = sums + (size_t)T_STEPS * N_PAD * FDIM;
  float* h1   = cs + SEG;

  const int sum_grid = (N_NODES + 3) / 4;        // k_sum6: 4 waves/block
  const int ngrp     = (N_NODES + 63) / 64;      // 1563 64-node groups
  const dim3 sc_grid((N_NODES + 255) / 256, T_STEPS);

  hipMemsetAsync(head, 0xFF, (size_t)SEG * sizeof(int), stream);
  k_build<<<(N_EDGES + 255) / 256, 256, 0, stream>>>(src, dst, tix, head, edat);

  // Layer 1
  k_sum6<<<sum_grid, 256, 0, stream>>>(x, edat, head, sums, cs);
  k_scale<<<sc_grid, 256, 0, stream>>>(sums, cs);
  k_gemm_b<64, 16><<<ngrp, 256, 0, stream>>>(sums, cs, W1, b1, h1);

  // Layer 2 (same edge lists; cs rewritten as cnt by sum6, re-transformed)
  k_sum6<<<sum_grid, 256, 0, stream>>>(h1, edat, head, sums, cs);
  k_scale<<<sc_grid, 256, 0, stream>>>(sums, cs);
  k_gemm_b<16, 4><<<ngrp, 256, 0, stream>>>(sums, cs, W2, b2, (float*)d_out);
}